// Round 14
// baseline (237.533 us; speedup 1.0000x reference)
//
#include <hip/hip_runtime.h>
#include <math.h>

#define BB   2
#define CFI  32
#define NN   36864          // 192*192
#define NUMM 16

// workspace (packed bf16 pairs): Y at wsu[0..], Z at wsu[ZOFSU..]
// per point: 16 u32 = 32 channels. u32 idx = hi*8 + q*2 + pair,
// channel c = 8q + 4hi + 2pair + {lo,hi16}.
#define ZOFSU (BB * NN * 16)

typedef __attribute__((ext_vector_type(8))) short short8;   // 8 bf16 (4 VGPRs)
typedef __attribute__((ext_vector_type(4))) float f4;       // 4 f32
typedef __attribute__((ext_vector_type(2))) unsigned u2v;

static __device__ __forceinline__ f4 mm16(short8 a, short8 b, f4 c) {
    return __builtin_amdgcn_mfma_f32_16x16x32_bf16(a, b, c, 0, 0, 0);
}

// DPP-based 16-lane-row reductions (VALU latency, no LDS pipe).
template <int CTRL>
static __device__ __forceinline__ float dpp_add(float x) {
    int y = __builtin_amdgcn_update_dpp(0, __builtin_bit_cast(int, x),
                                        CTRL, 0xf, 0xf, true);
    return x + __builtin_bit_cast(float, y);
}
template <int CTRL>
static __device__ __forceinline__ float dpp_max(float x) {
    int y = __builtin_amdgcn_update_dpp(0, __builtin_bit_cast(int, x),
                                        CTRL, 0xf, 0xf, true);
    return fmaxf(x, __builtin_bit_cast(float, y));
}

// tanh-form gelu: x * sigmoid(1.595769x + 0.0713548x^3), exp2-folded.
static __device__ __forceinline__ float gelu_fast(float x) {
    const float x2  = x * x;
    const float q   = fmaf(-0.10294310f, x2, -2.30211813f);
    const float e   = exp2f(q * x);
    const float r   = __builtin_amdgcn_rcpf(e + 1.0f);
    return x * r;
}

static __device__ __forceinline__ unsigned bf16_rne_bits(float x) {
    unsigned u = __builtin_bit_cast(unsigned, x);
    return u + 0x7fffu + ((u >> 16) & 1u);
}
static __device__ __forceinline__ void split_pack(float x0, float x1,
                                                  unsigned& hi, unsigned& lo) {
    unsigned r0 = bf16_rne_bits(x0);
    unsigned r1 = bf16_rne_bits(x1);
    float h0 = __builtin_bit_cast(float, r0 & 0xffff0000u);
    float h1 = __builtin_bit_cast(float, r1 & 0xffff0000u);
    hi = (r0 >> 16) | (r1 & 0xffff0000u);
    unsigned s0 = bf16_rne_bits(x0 - h0);
    unsigned s1 = bf16_rne_bits(x1 - h1);
    lo = (s0 >> 16) | (s1 & 0xffff0000u);
}

// cheap round-half-up bf16 pair pack (activations / workspace)
static __device__ __forceinline__ unsigned pack2(float a, float b) {
    unsigned ua = __builtin_bit_cast(unsigned, a) + 0x8000u;
    unsigned ub = __builtin_bit_cast(unsigned, b) + 0x8000u;
    return (ua >> 16) | (ub & 0xffff0000u);
}
static __device__ __forceinline__ float bflo(unsigned u) {
    return __builtin_bit_cast(float, u << 16);
}
static __device__ __forceinline__ float bfhi(unsigned u) {
    return __builtin_bit_cast(float, u & 0xffff0000u);
}

union UV { unsigned u[4]; short8 v; };

// ---- kernel A: per-point Y/Z precompute, packed-bf16 output ---------------
__global__ __launch_bounds__(256) void yz_kernel(
    const float* __restrict__ If, const float* __restrict__ Pf,
    const float* __restrict__ W1, const float* __restrict__ g1,
    const float* __restrict__ b1, const float* __restrict__ m1,
    const float* __restrict__ v1,
    float* __restrict__ wsYZ)
{
    __shared__ float wy[1024], wz[1024], wp[32], bt1[32];
    for (int i = threadIdx.x; i < 1024; i += 256) {
        int o = i >> 5, c = i & 31;
        float inv = g1[o] * rsqrtf(v1[o] + 1e-5f);
        wy[i] = W1[o * 67 + c]      * inv;
        wz[i] = W1[o * 67 + 32 + c] * inv;
    }
    if (threadIdx.x < 32) {
        int o = threadIdx.x;
        float inv = g1[o] * rsqrtf(v1[o] + 1e-5f);
        wp[o]  = W1[o * 67 + 64] * inv;
        bt1[o] = b1[o] - m1[o] * inv;
    }
    __syncthreads();

    const int r  = threadIdx.x & 3;
    const int p  = blockIdx.x * 64 + (threadIdx.x >> 2);
    const int b  = p / NN, n = p - b * NN;
    const int o0 = r * 8;
    const float* ifp = If + (size_t)b * CFI * NN + n;

    float v[32];
#pragma unroll
    for (int c = 0; c < 32; c++) v[c] = ifp[(size_t)c * NN];
    const float pf = Pf[p];

    float accY[8], accZ[8];
#pragma unroll
    for (int j = 0; j < 8; j++) {
        const float4* wyr = (const float4*)&wy[(o0 + j) * 32];
        const float4* wzr = (const float4*)&wz[(o0 + j) * 32];
        float ay = bt1[o0 + j];
        float az = wp[o0 + j] * pf;
#pragma unroll
        for (int c4 = 0; c4 < 8; c4++) {
            float4 a = wyr[c4], z = wzr[c4];
            ay = fmaf(a.x, v[4 * c4 + 0], ay);  az = fmaf(z.x, v[4 * c4 + 0], az);
            ay = fmaf(a.y, v[4 * c4 + 1], ay);  az = fmaf(z.y, v[4 * c4 + 1], az);
            ay = fmaf(a.z, v[4 * c4 + 2], ay);  az = fmaf(z.z, v[4 * c4 + 2], az);
            ay = fmaf(a.w, v[4 * c4 + 3], ay);  az = fmaf(z.w, v[4 * c4 + 3], az);
        }
        accY[j] = ay; accZ[j] = az;
    }

    // pack to bf16 pairs. thread r owns channels c = 8r + j (q == r):
    // j=0..3 -> hi=0 (u32 idx 2r, 2r+1), j=4..7 -> hi=1 (idx 8+2r, 8+2r+1).
    unsigned* wsu = (unsigned*)wsYZ;
    u2v yA, yB, zA, zB;
    yA[0] = pack2(accY[0], accY[1]); yA[1] = pack2(accY[2], accY[3]);
    yB[0] = pack2(accY[4], accY[5]); yB[1] = pack2(accY[6], accY[7]);
    zA[0] = pack2(accZ[0], accZ[1]); zA[1] = pack2(accZ[2], accZ[3]);
    zB[0] = pack2(accZ[4], accZ[5]); zB[1] = pack2(accZ[6], accZ[7]);
    *(u2v*)(wsu + (size_t)p * 16 + 2 * r)          = yA;
    *(u2v*)(wsu + (size_t)p * 16 + 8 + 2 * r)      = yB;
    *(u2v*)(wsu + ZOFSU + (size_t)p * 16 + 2 * r)     = zA;
    *(u2v*)(wsu + ZOFSU + (size_t)p * 16 + 8 + 2 * r) = zB;
}

// ---- kernel B: 16x16x32 MFMA MLP, 1 pt/pass, psi-relabeled, zero-shuffle --
// r26: 32x32 working set pinned occupancy at 42-43% across ALL bounds/reg
// cuts (r2..r12); r0's 16x16 shape measured 70% occ on this HW. Apply the
// phi-trick to 16x16: psi(g,j) = 16*(j>>2) + 4g + (j&3) is a bijection
// whose per-lane channel set {4g+r, 16+4g+r} == the C rows the lane holds
// (row=4g+reg, tiles T=0/1). A-init uses psi => relayout = 8 gelu + 4
// pack2, zero cross-lane (r0's structure minus its 16 bpermutes/point).
// acc 16->8, B 8->4, P 8->4, y/z carries 16->8: est ~75 live regs.
// r27: FIX r13 compile error — local `g4` shadowed the kernel param g4
// (layer-4 gamma); renamed to gq4. No other change.
#define LOADL16(Lc)                                                           \
    {                                                                         \
        A0l = *(const short8*)&wfrag[(Lc)][0][1][lane + io][0];               \
        A0h = *(const short8*)&wfrag[(Lc)][0][0][lane + io][0];               \
        A1l = *(const short8*)&wfrag[(Lc)][1][1][lane + io][0];               \
        A1h = *(const short8*)&wfrag[(Lc)][1][0][lane + io][0];               \
    }

#define LAYER16(Lc, BV, ACC0, ACC1)                                           \
    {                                                                         \
        f4 t0_ = *(const f4*)&btl[(Lc) * 32 + gq4 + 4 * io];                  \
        f4 t1_ = *(const f4*)&btl[(Lc) * 32 + 16 + gq4 + 4 * io];             \
        ACC0 = mm16(A0l, BV.v, t0_);                                          \
        ACC0 = mm16(A0h, BV.v, ACC0);                                         \
        ACC1 = mm16(A1l, BV.v, t1_);                                          \
        ACC1 = mm16(A1h, BV.v, ACC1);                                         \
    }

// C regs (channels 4g+r in ACC0, 16+4g+r in ACC1) -> next-layer B (psi order)
#define RELAYOUT16(ACC0, ACC1, BV)                                            \
    {                                                                         \
        BV.u[0] = pack2(gelu_fast(ACC0[0]), gelu_fast(ACC0[1]));              \
        BV.u[1] = pack2(gelu_fast(ACC0[2]), gelu_fast(ACC0[3]));              \
        BV.u[2] = pack2(gelu_fast(ACC1[0]), gelu_fast(ACC1[1]));              \
        BV.u[3] = pack2(gelu_fast(ACC1[2]), gelu_fast(ACC1[3]));              \
    }

__global__ __launch_bounds__(256, 5) void main_kernel(
    const float* __restrict__ Pf, const float* __restrict__ Of,
    const int* __restrict__ args,
    const float* __restrict__ W1, const float* __restrict__ g1,
    const float* __restrict__ v1,
    const float* __restrict__ W2, const float* __restrict__ g2,
    const float* __restrict__ b2, const float* __restrict__ m2,
    const float* __restrict__ v2,
    const float* __restrict__ W3, const float* __restrict__ g3,
    const float* __restrict__ b3, const float* __restrict__ m3,
    const float* __restrict__ v3,
    const float* __restrict__ W4, const float* __restrict__ g4,
    const float* __restrict__ b4, const float* __restrict__ m4,
    const float* __restrict__ v4,
    const float* __restrict__ Wc, const float* __restrict__ bc,
    const float* __restrict__ ws, float* __restrict__ out)
{
    __shared__ __align__(16) unsigned wfrag[3][2][2][64][4]; // L,T,hi/lo,lane,pair
    __shared__ __align__(16) float btl[3 * 32];   // BN beta by [L][ch]
    __shared__ __align__(16) float wch[3 * 32];   // Wc rows A,B,O by ch
    __shared__ __align__(16) float w1t[2 * 32];   // W1 cols 65,66 folded, by ch
    __shared__ float bcs[3];
    __shared__ int   izs;

    const float* Ws[3] = {W2, W3, W4};
    const float* gs[3] = {g2, g3, g4};
    const float* vs[3] = {v2, v3, v4};
    const float* bs[3] = {b2, b3, b4};
    const float* ms[3] = {m2, m3, m4};

    // A-frag init with psi(g,j) = 16*(j>>2) + 4g + (j&3); pair pp holds
    // j = 2pp, 2pp+1  =>  k = 16*(pp>>1) + 4g + 2*(pp&1) + {0,1}.
    for (int idx = threadIdx.x; idx < 1536; idx += 256) {
        int pp  = idx & 3;
        int ln  = (idx >> 2) & 63;
        int T   = (idx >> 8) & 1;
        int L   = idx >> 9;
        int o   = T * 16 + (ln & 15);
        int gg  = ln >> 4;
        int k   = 16 * (pp >> 1) + 4 * gg + 2 * (pp & 1);
        float inv = gs[L][o] * rsqrtf(vs[L][o] + 1e-5f);
        float w0 = Ws[L][o * 32 + k]     * inv;
        float w1 = Ws[L][o * 32 + k + 1] * inv;
        unsigned hiw, low;
        split_pack(w0, w1, hiw, low);
        wfrag[L][T][0][ln][pp] = hiw;
        wfrag[L][T][1][ln][pp] = low;
    }
    if (threadIdx.x < 96) {
        int L = threadIdx.x >> 5, ch = threadIdx.x & 31;
        btl[threadIdx.x] = bs[L][ch] - ms[L][ch] * (gs[L][ch] * rsqrtf(vs[L][ch] + 1e-5f));
        wch[threadIdx.x] = Wc[L * 32 + ch];
    }
    if (threadIdx.x < 64) {
        int t = threadIdx.x >> 5, ch = threadIdx.x & 31;
        float i1 = g1[ch] * rsqrtf(v1[ch] + 1e-5f);
        w1t[threadIdx.x] = W1[ch * 67 + 65 + t] * i1;
    }
    if (threadIdx.x < 3) bcs[threadIdx.x] = bc[threadIdx.x];
    if (threadIdx.x == 0) izs = (int)(args[0] >> 16);   // == 0, opaque
    __syncthreads();

    const unsigned* wsu = (const unsigned*)ws;
    const int lane  = threadIdx.x & 63;
    const int wid   = threadIdx.x >> 6;
    const int m     = lane & 15;          // m-index (softmax axis & B col)
    const int gl    = lane >> 4;          // lane group
    const int gq4   = gl << 2;            // 4*g
    const int uA    = (gl & 1) * 8 + (gl >> 1) * 2;  // y/z u32 base for chans 4g..
    const int izero = izs;                // 0, compiler-opaque

    const int base  = blockIdx.x * 16 + wid * 4;   // 4 points per wave

    // ---- pipeline carries (loaded for iter 0 here; refilled post-L1) ------
    u2v yA, yB, zA, zB;
    float of0v, of1v, pfg_n;
    int   aI_n;
    {
        const int C0 = base;
        const int b0 = (C0 >= NN) ? 1 : 0;
        const int n0 = C0 - b0 * NN;
        const int a0 = args[(b0 * NUMM + m) * NN + n0];
        of0v = Of[((b0 * 2 + 0) * NUMM + m) * NN + n0];
        of1v = Of[((b0 * 2 + 1) * NUMM + m) * NN + n0];
        pfg_n = Pf[b0 * NN + a0];
        const unsigned* yr = wsu + (size_t)(b0 * NN + n0) * 16;
        const unsigned* zr = wsu + ZOFSU + (size_t)(b0 * NN + a0) * 16;
        yA = *(const u2v*)(yr + uA); yB = *(const u2v*)(yr + uA + 4);
        zA = *(const u2v*)(zr + uA); zB = *(const u2v*)(zr + uA + 4);
        // args for iter 1
        const int C1 = (C0 + 1 < BB * NN) ? C0 + 1 : BB * NN - 1;
        const int b1_ = (C1 >= NN) ? 1 : 0;
        const int n1_ = C1 - b1_ * NN;
        aI_n = args[(b1_ * NUMM + m) * NN + n1_];
    }

#pragma unroll 1
    for (int i = 0; i < 4; i++) {
        const int io = i & izero;                         // 0 every iter, unprovable
        const int C  = base + i;
        const int b  = (C >= NN) ? 1 : 0;
        const int n  = C - b * NN;
        const float pfg = pfg_n;                          // consumed in epilogue

        short8 A0l, A0h, A1l, A1h;
        LOADL16(0);                                       // covered by L1 math

        // ---- layer 1: h1 channels {4g+r, 16+4g+r} -> B fragment (psi) ------
        const f4 walo = *(const f4*)&w1t[gq4 + 4 * io];
        const f4 wahi = *(const f4*)&w1t[16 + gq4 + 4 * io];
        const f4 wblo = *(const f4*)&w1t[32 + gq4 + 4 * io];
        const f4 wbhi = *(const f4*)&w1t[48 + gq4 + 4 * io];
        UV B0;
        {
            float x0 = fmaf(of1v, wblo[0], fmaf(of0v, walo[0], bflo(yA[0]) + bflo(zA[0])));
            float x1 = fmaf(of1v, wblo[1], fmaf(of0v, walo[1], bfhi(yA[0]) + bfhi(zA[0])));
            float x2 = fmaf(of1v, wblo[2], fmaf(of0v, walo[2], bflo(yA[1]) + bflo(zA[1])));
            float x3 = fmaf(of1v, wblo[3], fmaf(of0v, walo[3], bfhi(yA[1]) + bfhi(zA[1])));
            float x4 = fmaf(of1v, wbhi[0], fmaf(of0v, wahi[0], bflo(yB[0]) + bflo(zB[0])));
            float x5 = fmaf(of1v, wbhi[1], fmaf(of0v, wahi[1], bfhi(yB[0]) + bfhi(zB[0])));
            float x6 = fmaf(of1v, wbhi[2], fmaf(of0v, wahi[2], bflo(yB[1]) + bflo(zB[1])));
            float x7 = fmaf(of1v, wbhi[3], fmaf(of0v, wahi[3], bfhi(yB[1]) + bfhi(zB[1])));
            B0.u[0] = pack2(gelu_fast(x0), gelu_fast(x1));
            B0.u[1] = pack2(gelu_fast(x2), gelu_fast(x3));
            B0.u[2] = pack2(gelu_fast(x4), gelu_fast(x5));
            B0.u[3] = pack2(gelu_fast(x6), gelu_fast(x7));
        }

        // ---- max-cover prefetch for iter i+1 (consumed at next L1) --------
        {
            const int Cn = (C + 1 < BB * NN) ? C + 1 : BB * NN - 1;
            const int bn = (Cn >= NN) ? 1 : 0;
            const int nn = Cn - bn * NN;
            const unsigned* yrn = wsu + (size_t)(bn * NN + nn) * 16;
            yA = *(const u2v*)(yrn + uA); yB = *(const u2v*)(yrn + uA + 4);
            of0v = Of[((bn * 2 + 0) * NUMM + m) * NN + nn];
            of1v = Of[((bn * 2 + 1) * NUMM + m) * NN + nn];
            const int aN = aI_n;
            pfg_n = Pf[bn * NN + aN];
            const unsigned* zrn = wsu + ZOFSU + (size_t)(bn * NN + aN) * 16;
            zA = *(const u2v*)(zrn + uA); zB = *(const u2v*)(zrn + uA + 4);
            const int Ca = (C + 2 < BB * NN) ? C + 2 : BB * NN - 1;
            const int ba = (Ca >= NN) ? 1 : 0;
            const int na = Ca - ba * NN;
            aI_n = args[(ba * NUMM + m) * NN + na];
        }

        // ---- layer 2 ----
        f4 acc0, acc1;
        LAYER16(0, B0, acc0, acc1);
        LOADL16(1);                                       // covered by gelu(h2)
        UV P0;                                            // packed gelu(h2)
        RELAYOUT16(acc0, acc1, P0);
        B0 = P0;

        // ---- layer 3 ----
        LAYER16(1, B0, acc0, acc1);
        LOADL16(2);                                       // covered by gelu(h3)
        RELAYOUT16(acc0, acc1, B0);

        // ---- layer 4 + residual + head ----
        LAYER16(2, B0, acc0, acc1);

        const f4 wcAl = *(const f4*)&wch[gq4 + 4 * io];
        const f4 wcAh = *(const f4*)&wch[16 + gq4 + 4 * io];
        const f4 wcBl = *(const f4*)&wch[32 + gq4 + 4 * io];
        const f4 wcBh = *(const f4*)&wch[48 + gq4 + 4 * io];
        const f4 wcOl = *(const f4*)&wch[64 + gq4 + 4 * io];
        const f4 wcOh = *(const f4*)&wch[80 + gq4 + 4 * io];

        float pa, pb, po;
        {
            float xf0 = gelu_fast(bflo(P0.u[0]) + acc0[0]);
            float xf1 = gelu_fast(bfhi(P0.u[0]) + acc0[1]);
            float xf2 = gelu_fast(bflo(P0.u[1]) + acc0[2]);
            float xf3 = gelu_fast(bfhi(P0.u[1]) + acc0[3]);
            float xf4 = gelu_fast(bflo(P0.u[2]) + acc1[0]);
            float xf5 = gelu_fast(bfhi(P0.u[2]) + acc1[1]);
            float xf6 = gelu_fast(bflo(P0.u[3]) + acc1[2]);
            float xf7 = gelu_fast(bfhi(P0.u[3]) + acc1[3]);
            pa = wcAl[0] * xf0; pb = wcBl[0] * xf0; po = wcOl[0] * xf0;
            pa = fmaf(wcAl[1], xf1, pa); pb = fmaf(wcBl[1], xf1, pb); po = fmaf(wcOl[1], xf1, po);
            pa = fmaf(wcAl[2], xf2, pa); pb = fmaf(wcBl[2], xf2, pb); po = fmaf(wcOl[2], xf2, po);
            pa = fmaf(wcAl[3], xf3, pa); pb = fmaf(wcBl[3], xf3, pb); po = fmaf(wcOl[3], xf3, po);
            pa = fmaf(wcAh[0], xf4, pa); pb = fmaf(wcBh[0], xf4, pb); po = fmaf(wcOh[0], xf4, po);
            pa = fmaf(wcAh[1], xf5, pa); pb = fmaf(wcBh[1], xf5, pb); po = fmaf(wcOh[1], xf5, po);
            pa = fmaf(wcAh[2], xf6, pa); pb = fmaf(wcBh[2], xf6, pb); po = fmaf(wcOh[2], xf6, po);
            pa = fmaf(wcAh[3], xf7, pa); pb = fmaf(wcBh[3], xf7, pb); po = fmaf(wcOh[3], xf7, po);
        }
        // reduce over the 4 lane-groups g (channels partition): lanes m+16g
        pa += __shfl_xor(pa, 16, 64);  pa += __shfl_xor(pa, 32, 64);
        pb += __shfl_xor(pb, 16, 64);  pb += __shfl_xor(pb, 32, 64);
        po += __shfl_xor(po, 16, 64);  po += __shfl_xor(po, 32, 64);

        const float alpha = pa + bcs[0];
        const float beta_ = pb + bcs[1];
        const float omega = po + bcs[2];
        const float val = fmaf(alpha + 1.0f, pfg, beta_);

        // softmax over the 16 m's — DPP row reductions (VALU latency)
        float mx = dpp_max<0xB1>(omega);
        mx = dpp_max<0x4E>(mx);
        mx = dpp_max<0x141>(mx);
        mx = dpp_max<0x140>(mx);
        const float e = __expf(omega - mx);
        float S = e, T = val * e;
        S = dpp_add<0xB1>(S);   T = dpp_add<0xB1>(T);
        S = dpp_add<0x4E>(S);   T = dpp_add<0x4E>(T);
        S = dpp_add<0x141>(S);  T = dpp_add<0x141>(T);
        S = dpp_add<0x140>(S);  T = dpp_add<0x140>(T);

        if (lane == 0)
            out[b * NN + n] = T * __builtin_amdgcn_rcpf(S);
    }
}

// ---- launcher ---------------------------------------------------------------
extern "C" void kernel_launch(void* const* d_in, const int* in_sizes, int n_in,
                              void* d_out, int out_size, void* d_ws, size_t ws_size,
                              hipStream_t stream) {
    const float* If    = (const float*)d_in[0];
    const float* Pf    = (const float*)d_in[1];
    const float* Of    = (const float*)d_in[2];
    const int*   args  = (const int*)d_in[3];
    const float* W1    = (const float*)d_in[4];
    const float* g1    = (const float*)d_in[5];
    const float* b1    = (const float*)d_in[6];
    const float* m1    = (const float*)d_in[7];
    const float* v1    = (const float*)d_in[8];
    const float* W2    = (const float*)d_in[9];
    const float* g2    = (const float*)d_in[10];
    const float* b2    = (const float*)d_in[11];
    const float* m2    = (const float*)d_in[12];
    const float* v2    = (const float*)d_in[13];
    const float* W3    = (const float*)d_in[14];
    const float* g3    = (const float*)d_in[15];
    const float* b3    = (const float*)d_in[16];
    const float* m3    = (const float*)d_in[17];
    const float* v3    = (const float*)d_in[18];
    const float* W4    = (const float*)d_in[19];
    const float* g4    = (const float*)d_in[20];
    const float* b4    = (const float*)d_in[21];
    const float* m4    = (const float*)d_in[22];
    const float* v4    = (const float*)d_in[23];
    const float* Wc    = (const float*)d_in[24];
    const float* bc    = (const float*)d_in[25];

    float* ws  = (float*)d_ws;
    float* out = (float*)d_out;

    yz_kernel<<<(BB * NN) / 64, 256, 0, stream>>>(
        If, Pf, W1, g1, b1, m1, v1, ws);

    main_kernel<<<(BB * NN) / 16, 256, 0, stream>>>(
        Pf, Of, args,
        W1, g1, v1,
        W2, g2, b2, m2, v2,
        W3, g3, b3, m3, v3,
        W4, g4, b4, m4, v4,
        Wc, bc, ws, out);
}